// Round 1
// baseline (35.797 us; speedup 1.0000x reference)
//
#include <hip/hip_runtime.h>

namespace {

constexpr int IMGW = 512;
constexpr int NIMG = 16;
constexpr int C1N  = 16;
constexpr int C2N  = 32;
constexpr int NBLK = 1024;        // 16 images * 64 patch-rows
constexpr int PART = C1N * 9;     // 144 partial scalars per block

// 8x8 DCT-II (orthonormal) matrix, f32-exact literals.
constexpr float DCTM[8][8] = {
  {0.35355339059327373f, 0.35355339059327373f, 0.35355339059327373f, 0.35355339059327373f,
   0.35355339059327373f, 0.35355339059327373f, 0.35355339059327373f, 0.35355339059327373f},
  {0.49039264020161522f, 0.41573480615127262f, 0.27778511650980111f, 0.09754516100806413f,
  -0.09754516100806413f,-0.27778511650980111f,-0.41573480615127262f,-0.49039264020161522f},
  {0.46193976625564337f, 0.19134171618254492f,-0.19134171618254492f,-0.46193976625564337f,
  -0.46193976625564337f,-0.19134171618254492f, 0.19134171618254492f, 0.46193976625564337f},
  {0.41573480615127262f,-0.09754516100806413f,-0.49039264020161522f,-0.27778511650980111f,
   0.27778511650980111f, 0.49039264020161522f, 0.09754516100806413f,-0.41573480615127262f},
  {0.35355339059327373f,-0.35355339059327373f,-0.35355339059327373f, 0.35355339059327373f,
   0.35355339059327373f,-0.35355339059327373f,-0.35355339059327373f, 0.35355339059327373f},
  {0.27778511650980111f,-0.49039264020161522f, 0.09754516100806413f, 0.41573480615127262f,
  -0.41573480615127262f,-0.09754516100806413f, 0.49039264020161522f,-0.27778511650980111f},
  {0.19134171618254492f,-0.46193976625564337f, 0.46193976625564337f,-0.19134171618254492f,
  -0.19134171618254492f, 0.46193976625564337f,-0.46193976625564337f, 0.19134171618254492f},
  {0.09754516100806413f,-0.27778511650980111f, 0.41573480615127262f,-0.49039264020161522f,
   0.49039264020161522f,-0.41573480615127262f, 0.27778511650980111f,-0.09754516100806413f},
};

// One block = one patch-row (64 patches) of one image; 4 waves.
// Each wave handles the SAME 64 patches (lane = patch column) but a
// different 4-channel slice of conv1. DCT recomputed per wave (cheap).
// Per-channel, per-patch we only need 9 scalars (T, R0, R7, C0, C7, 4
// corners); everything downstream (conv2 + both means) is linear and is
// folded into the finish kernel via inclusion-exclusion border sums.
__global__ __launch_bounds__(256) void dct_conv_kernel(
    const float* __restrict__ x, const float* __restrict__ w1,
    const float* __restrict__ b1, float* __restrict__ partials)
{
  const int blk  = blockIdx.x;
  const int img  = blk >> 6;
  const int prow = blk & 63;
  const int lane = threadIdx.x & 63;   // patch column 0..63
  const int wave = threadIdx.x >> 6;   // 0..3 -> channel group

  const float* base = x + ((size_t)img * IMGW + (size_t)prow * 8) * IMGW + (size_t)lane * 8;

  // Load 8x8 patch (two float4 per row; lanes stride 32B -> full lines used)
  float p[8][8];
  #pragma unroll
  for (int r = 0; r < 8; ++r) {
    const float4 a = *reinterpret_cast<const float4*>(base + (size_t)r * IMGW);
    const float4 b = *reinterpret_cast<const float4*>(base + (size_t)r * IMGW + 4);
    p[r][0] = a.x; p[r][1] = a.y; p[r][2] = a.z; p[r][3] = a.w;
    p[r][4] = b.x; p[r][5] = b.y; p[r][6] = b.z; p[r][7] = b.w;
  }

  // t = DCT * p
  float t[8][8];
  #pragma unroll
  for (int i = 0; i < 8; ++i) {
    #pragma unroll
    for (int j = 0; j < 8; ++j) {
      float s = DCTM[i][0] * p[0][j];
      #pragma unroll
      for (int k = 1; k < 8; ++k) s = fmaf(DCTM[i][k], p[k][j], s);
      t[i][j] = s;
    }
  }
  // cf = t * DCT^T
  float cf[8][8];
  #pragma unroll
  for (int i = 0; i < 8; ++i) {
    #pragma unroll
    for (int j = 0; j < 8; ++j) {
      float s = t[i][0] * DCTM[j][0];
      #pragma unroll
      for (int k = 1; k < 8; ++k) s = fmaf(t[i][k], DCTM[j][k], s);
      cf[i][j] = s;
    }
  }

  // conv1 (3x3 SAME, 1->16ch) + ReLU; this wave's 4 channels.
  for (int cc = 0; cc < 4; ++cc) {
    const int ch = wave * 4 + cc;
    float w[9];
    #pragma unroll
    for (int q = 0; q < 9; ++q) w[q] = w1[ch * 9 + q];
    const float bb = b1[ch];

    float T = 0.f, R0 = 0.f, R7 = 0.f, Cs0 = 0.f, Cs7 = 0.f;
    float K00 = 0.f, K07 = 0.f, K70 = 0.f, K77 = 0.f;
    #pragma unroll
    for (int i = 0; i < 8; ++i) {
      #pragma unroll
      for (int j = 0; j < 8; ++j) {
        float a = bb;
        #pragma unroll
        for (int di = 0; di < 3; ++di) {
          const int ii = i + di - 1;
          if (ii >= 0 && ii < 8) {
            #pragma unroll
            for (int dj = 0; dj < 3; ++dj) {
              const int jj = j + dj - 1;
              if (jj >= 0 && jj < 8) a = fmaf(w[di * 3 + dj], cf[ii][jj], a);
            }
          }
        }
        a = fmaxf(a, 0.f);
        T += a;
        if (i == 0) R0 += a;
        if (i == 7) R7 += a;
        if (j == 0) Cs0 += a;
        if (j == 7) Cs7 += a;
        if (i == 0 && j == 0) K00 = a;
        if (i == 0 && j == 7) K07 = a;
        if (i == 7 && j == 0) K70 = a;
        if (i == 7 && j == 7) K77 = a;
      }
    }

    float v[9] = {T, R0, R7, Cs0, Cs7, K00, K07, K70, K77};
    #pragma unroll
    for (int q = 0; q < 9; ++q) {
      float s = v[q];
      #pragma unroll
      for (int m = 32; m >= 1; m >>= 1) s += __shfl_xor(s, m, 64);
      v[q] = s;
    }
    if (lane == 0) {
      #pragma unroll
      for (int q = 0; q < 9; ++q) partials[(size_t)blk * PART + ch * 9 + q] = v[q];
    }
  }
}

// Per image: sum the 64 block-partials (fixed order, deterministic), then
// contract with w2 via inclusion-exclusion border sums.
__global__ __launch_bounds__(192) void finish_kernel(
    const float* __restrict__ w2, const float* __restrict__ b2,
    const float* __restrict__ partials, float* __restrict__ out)
{
  const int img = blockIdx.x;
  const int tid = threadIdx.x;
  __shared__ float acc[C1N][9];
  if (tid < PART) {
    float s = 0.f;
    for (int k = 0; k < 64; ++k) s += partials[(size_t)(img * 64 + k) * PART + tid];
    acc[tid / 9][tid % 9] = s;
  }
  __syncthreads();
  if (tid < C2N) {
    float r = 0.f;
    for (int c1 = 0; c1 < C1N; ++c1) {
      const float T  = acc[c1][0], R0 = acc[c1][1], R7 = acc[c1][2];
      const float Q0 = acc[c1][3], Q7 = acc[c1][4];
      const float K00 = acc[c1][5], K07 = acc[c1][6], K70 = acc[c1][7], K77 = acc[c1][8];
      const float* wp = w2 + (size_t)(tid * C1N + c1) * 9;
      #pragma unroll
      for (int di = 0; di < 3; ++di) {
        #pragma unroll
        for (int dj = 0; dj < 3; ++dj) {
          float S = T;
          if (di == 0) S -= R7;
          if (di == 2) S -= R0;
          if (dj == 0) S -= Q7;
          if (dj == 2) S -= Q0;
          if (di == 0 && dj == 0) S += K77;
          if (di == 0 && dj == 2) S += K70;
          if (di == 2 && dj == 0) S += K07;
          if (di == 2 && dj == 2) S += K00;
          r = fmaf(wp[di * 3 + dj], S, r);
        }
      }
    }
    out[img * C2N + tid] = b2[tid] + r * (1.0f / 262144.0f);
  }
}

} // namespace

extern "C" void kernel_launch(void* const* d_in, const int* in_sizes, int n_in,
                              void* d_out, int out_size, void* d_ws, size_t ws_size,
                              hipStream_t stream) {
  const float* x  = (const float*)d_in[0];
  const float* w1 = (const float*)d_in[1];
  const float* b1 = (const float*)d_in[2];
  const float* w2 = (const float*)d_in[3];
  const float* b2 = (const float*)d_in[4];
  float* out      = (float*)d_out;
  float* partials = (float*)d_ws;   // NBLK * PART floats = 576 KB

  dct_conv_kernel<<<NBLK, 256, 0, stream>>>(x, w1, b1, partials);
  finish_kernel<<<NIMG, 192, 0, stream>>>(w2, b2, partials, out);
}